// Round 6
// baseline (271.679 us; speedup 1.0000x reference)
//
#include <hip/hip_runtime.h>
#include <math.h>

#define RENDER 256
#define IMG_H 480
#define IMG_W 640
#define NV 2048
#define NF 4096
#define FACE_SLICES 16
#define FACES_PER_SLICE (NF / FACE_SLICES)       // 256
#define TILES_X 16
#define TILES_Y_LIVE 12            // crop samples render rows <= 191 only:
                                   // (2*479+1)/5 = 191 -> tileY >= 12 is dead
#define TILES_LIVE (TILES_X * TILES_Y_LIVE)       // 192
#define N_UNITS (TILES_LIVE * FACE_SLICES)        // 3072 units
#define UNIT_HASH 2053             // odd, not div by 3 -> coprime to 3072

#define SIGMA_INV 2.0f                            // 1/SIGMA, SIGMA=0.5
#define CAP 13.815510557964274f                   // -log(1e-6)
#define LOG2E 1.4426950408889634f
#define ZK 2.8853900817779268f                    // SIGMA_INV * LOG2E
#define CAP2 19.931568569324174f                  // CAP * LOG2E = log2(1e6)
#define ECAP 999999.0f                            // 1e6 - 1: min(1+e,1e6) = 1+min(e,ECAP)
#define SKIP_PIX -26.0f                           // per-px contribution < 2.1e-8 in log2
// Per-edge exact tile bound: d_k varies over the 16x16 tile (pixel centers at
// tile-center +/- 7.5 px in each axis) by at most r_k = 7.5*(|A_k|+|B_k|),
// stored in the .w lane of each edge quad.
//   cap  everywhere: min_k (d_k(center) - r_k) > CAP2   (=> sp2 > CAP2 at every px)
//   skip everywhere: min_k (d_k(center) + r_k) < SKIP_PIX (some edge < -26 at every px)

// ws layout:
//   [0, 192KB)       fdata : 4096 faces * 12 floats (3 edges * {A,B,C,r})
//   [192KB, 448KB)   logp  : 65536 floats (log2-domain; rows 0..191 used)
//   [448KB, +768B)   done  : 192 ints, per-tile completion counters
#define WS_FD_OFF    0
#define WS_LOGP_OFF  (192 * 1024)
#define WS_DONE_OFF  (448 * 1024)

// ---------------- kernel 1: fused setup ----------------------------------
// blocks 0..15   : SE3 exp (redundant per thread) + project all verts into
//                  LDS (redundant per block) + per-face edge coefficients
//                  (prescaled by ZK into log2 domain) + per-edge tile radius
// blocks 16..207 : zero logp rows 0..191; block 16 also zeros out[0] and the
//                  192 per-tile completion counters (stream-ordered before
//                  kernel 2 starts).
__global__ __launch_bounds__(256) void k_prep(const float* __restrict__ dof,
                                              const float* __restrict__ verts,
                                              const int* __restrict__ faces,
                                              const float* __restrict__ Km,
                                              float* __restrict__ fdata,
                                              float* __restrict__ logp,
                                              int* __restrict__ done,
                                              float* __restrict__ out) {
    if (blockIdx.x >= 16) {
        logp[(blockIdx.x - 16) * 256 + threadIdx.x] = 0.0f;
        if (blockIdx.x == 16) {
            if (threadIdx.x == 0) out[0] = 0.0f;
            if (threadIdx.x < TILES_LIVE) done[threadIdx.x] = 0;
        }
        return;
    }

    __shared__ float sxy[NV * 2];   // 16 KB projected verts

    float v0 = dof[0], v1 = dof[1], v2 = dof[2];
    float w0 = dof[3], w1 = dof[4], w2 = dof[5];
    float th2 = w0 * w0 + w1 * w1 + w2 * w2;
    float th = sqrtf(th2 + 1e-30f);
    bool small = th < 1e-4f;
    float th_s = small ? 1.0f : th;
    float th2_s = small ? 1.0f : th2;
    float A = small ? (1.0f - th2 / 6.0f) : (sinf(th_s) / th_s);
    float B = small ? (0.5f - th2 / 24.0f) : ((1.0f - cosf(th_s)) / th2_s);
    float C = small ? (1.0f / 6.0f - th2 / 120.0f)
                    : ((th_s - sinf(th_s)) / (th2_s * th_s));
    float Kx[9] = {0.0f, -w2, w1, w2, 0.0f, -w0, -w1, w0, 0.0f};
    float w[3] = {w0, w1, w2};
    float R[9], V[9];
    for (int i = 0; i < 3; i++)
        for (int j = 0; j < 3; j++) {
            float K2 = w[i] * w[j] - (i == j ? th2 : 0.0f);
            float id = (i == j) ? 1.0f : 0.0f;
            R[i * 3 + j] = id + A * Kx[i * 3 + j] + B * K2;
            V[i * 3 + j] = id + B * Kx[i * 3 + j] + C * K2;
        }
    float t0 = V[0] * v0 + V[1] * v1 + V[2] * v2;
    float t1 = V[3] * v0 + V[4] * v1 + V[5] * v2;
    float t2 = V[6] * v0 + V[7] * v1 + V[8] * v2;
    float K00 = Km[0], K01 = Km[1], K02 = Km[2];
    float K10 = Km[3], K11 = Km[4], K12 = Km[5];
    float K20 = Km[6], K21 = Km[7], K22 = Km[8];
    const float scale = 256.0f / 640.0f;

    for (int n = threadIdx.x; n < NV; n += 256) {
        float vx = verts[n * 3], vy = verts[n * 3 + 1], vz = verts[n * 3 + 2];
        float cx = R[0] * vx + R[1] * vy + R[2] * vz + t0;
        float cy = R[3] * vx + R[4] * vy + R[5] * vz + t1;
        float cz = R[6] * vx + R[7] * vy + R[8] * vz + t2;
        float u = K00 * cx + K01 * cy + K02 * cz;
        float v = K10 * cx + K11 * cy + K12 * cz;
        float ww = K20 * cx + K21 * cy + K22 * cz;
        float rw = __builtin_amdgcn_rcpf(ww) * scale;   // rel err ~1e-7: 2e-5 px
        sxy[n * 2]     = u * rw;
        sxy[n * 2 + 1] = v * rw;
    }
    __syncthreads();

    int f = blockIdx.x * 256 + threadIdx.x;
    int i0 = faces[f * 3], i1 = faces[f * 3 + 1], i2 = faces[f * 3 + 2];
    float x0 = sxy[i0 * 2], y0 = sxy[i0 * 2 + 1];
    float x1 = sxy[i1 * 2], y1 = sxy[i1 * 2 + 1];
    float x2 = sxy[i2 * 2], y2 = sxy[i2 * 2 + 1];
    float ex[3] = {x1 - x0, x2 - x1, x0 - x2};
    float ey[3] = {y1 - y0, y2 - y1, y0 - y2};
    float ax[3] = {x0, x1, x2};
    float ay[3] = {y0, y1, y2};
    float area2 = ex[0] * (-ey[2]) - ey[0] * (-ex[2]);
    float sgn = (area2 >= 0.0f) ? 1.0f : -1.0f;
    float* o = fdata + f * 12;
    for (int k = 0; k < 3; k++) {
        float elen = sqrtf(ex[k] * ex[k] + ey[k] * ey[k]) + 1e-9f;
        float c0 = ex[k] * ay[k] - ey[k] * ax[k];
        float inv = sgn / elen * ZK;       // prescale into log2 domain
        float Ac = ex[k] * inv;            // A (py coeff)
        float Bc = -ey[k] * inv;           // B (px coeff)
        o[k * 4 + 0] = Ac;
        o[k * 4 + 1] = Bc;
        o[k * 4 + 2] = -c0 * inv;          // C
        o[k * 4 + 3] = 7.5f * (fabsf(Ac) + fabsf(Bc));   // r_k tile radius
    }
}

// ---------------- kernel 2: raster + fused final via completion counter --
// 3072 blocks x 256 threads: 192 live tiles x 16 face-slices, hash-scattered.
// Phases 1-3 identical to the verified R5 path. Then every unit (including
// empty ones) publishes completion: all threads __threadfence() (release all
// logp atomics), __syncthreads(), thread 0 increments done[tile]. The unit
// observing old == 15 is the tile's LAST: it re-reads the tile's 256 logp
// values with coherent RMW loads (atomicAdd(p, 0.0f) -- safe across XCD L2s)
// and runs the fused nearest-resize + crop + SSE epilogue for the tile's
// exclusive 40x40 output patch, then one atomicAdd into out[0].
__global__ __launch_bounds__(256) void k_raster(const float* __restrict__ fdata,
                                                float* __restrict__ logp,
                                                int* __restrict__ done,
                                                const float* __restrict__ mask,
                                                float* __restrict__ out) {
    // 16 KB, dual use:
    //   survivors: slots 0..259 of 12 floats  (3120 floats)
    //   reduction: 4 waves * 1024 tile-local-pixel floats (4096 floats)
    __shared__ float s_data[4096];
    __shared__ float s_si[256];
    __shared__ float s_red[4];
    __shared__ int s_n;
    __shared__ int s_ncap;
    __shared__ int s_last;
    const int tid = threadIdx.x;
    if (tid == 0) { s_n = 0; s_ncap = 0; }
    __syncthreads();

    const int unit = (int)((blockIdx.x * UNIT_HASH) % N_UNITS);
    const int tile = unit >> 4;            // 0..191 (row-major, 16 wide)
    const int slice = unit & 15;
    const int tileX = tile & 15;
    const int tileY = tile >> 4;           // 0..11
    const float cx = tileX * 16 + 8.0f;
    const float cy = tileY * 16 + 8.0f;
    const float4* __restrict__ fd4 = (const float4*)fdata;
    const int lane = tid & 63;

    // ---- phase 1: per-edge interval cull + ballot-compact ----
    {
        int f = slice * FACES_PER_SLICE + tid;
        float4 e0 = fd4[f * 3 + 0];
        float4 e1 = fd4[f * 3 + 1];
        float4 e2 = fd4[f * 3 + 2];
        float d0 = fmaf(e0.y, cx, fmaf(e0.x, cy, e0.z));
        float d1 = fmaf(e1.y, cx, fmaf(e1.x, cy, e1.z));
        float d2 = fmaf(e2.y, cx, fmaf(e2.x, cy, e2.z));
        float capm = fminf(d0 - e0.w, fminf(d1 - e1.w, d2 - e2.w));
        float skpm = fminf(d0 + e0.w, fminf(d1 + e1.w, d2 + e2.w));
        bool capped = capm > CAP2;                   // saturated at every px
        bool live = (!capped) && (skpm > SKIP_PIX);  // else negligible everywhere
        unsigned long long mcap = __ballot(capped);
        unsigned long long mliv = __ballot(live);
        int base = 0;
        if (lane == 0) {
            base = atomicAdd(&s_n, __popcll(mliv));
            if (mcap) atomicAdd(&s_ncap, __popcll(mcap));
        }
        base = __shfl(base, 0, 64);
        if (live) {
            int pos = base + __popcll(mliv & ((1ull << lane) - 1ull));
            float4* dst = (float4*)(s_data + pos * 12);
            dst[0] = e0; dst[1] = e1; dst[2] = e2;
        }
    }
    __syncthreads();

    const int n = s_n;
    const int ncap = s_ncap;
    const int wv = tid >> 6;
    const int row = lane >> 2;                       // 0..15
    const int col0 = lane & 3;                       // + {0,4,8,12}

    if (n != 0 || ncap != 0) {                       // non-empty unit
        // ---- phase 2: wave-split eval, 4 px/lane, product domain ----
        const float py = (float)(tileY * 16 + row) + 0.5f;
        const float px0 = (float)(tileX * 16 + col0) + 0.5f;

        float pm[4] = {1.0f, 1.0f, 1.0f, 1.0f};      // mantissa products
        int   pe[4] = {0, 0, 0, 0};                  // stripped exponents
        const float4* sd = (const float4*)s_data;
        if (wv < n) {
            float4 c0 = sd[wv * 3 + 0], c1 = sd[wv * 3 + 1], c2 = sd[wv * 3 + 2];
            int it = 0;
            for (int i = wv; i < n; i += 4) {
                // prefetch slot i+4 (slot <= 259 -> float < 3120 < 4096)
                float4 n0 = sd[(i + 4) * 3 + 0];
                float4 n1 = sd[(i + 4) * 3 + 1];
                float4 n2 = sd[(i + 4) * 3 + 2];
                float t0p = fmaf(c0.x, py, c0.z);  // py-terms shared by 4 px
                float t1p = fmaf(c1.x, py, c1.z);
                float t2p = fmaf(c2.x, py, c2.z);
                #pragma unroll
                for (int k = 0; k < 4; ++k) {
                    float px = px0 + (float)(4 * k);
                    float z = fminf(fmaf(c0.y, px, t0p),
                              fminf(fmaf(c1.y, px, t1p), fmaf(c2.y, px, t2p)));
                    float e = fminf(__builtin_amdgcn_exp2f(z), ECAP);
                    pm[k] = fmaf(pm[k], e, pm[k]);   // pm *= (1 + e), capped
                }
                if (((++it) & 3) == 0) {             // strip exp every 4 faces
                    #pragma unroll
                    for (int k = 0; k < 4; ++k) {
                        unsigned b = __float_as_uint(pm[k]);
                        pe[k] += (int)(b >> 23) - 127;
                        pm[k] = __uint_as_float((b & 0x007fffffu) | 0x3f800000u);
                    }
                }
                c0 = n0; c1 = n1; c2 = n2;
            }
        }
        float acc[4];
        #pragma unroll
        for (int k = 0; k < 4; ++k)
            acc[k] = -((float)pe[k] + __builtin_amdgcn_logf(pm[k]));

        // ---- phase 3: LDS-reduce 4 wave partials, 1 atomic per px ----
        __syncthreads();                  // all waves done reading survivors
        {
            int base = wv * 1024 + row * 16 + col0;
            s_data[base + 0]  = acc[0];
            s_data[base + 4]  = acc[1];
            s_data[base + 8]  = acc[2];
            s_data[base + 12] = acc[3];
        }
        __syncthreads();
        {
            int p = tid;                              // tile-local pixel
            float v = s_data[p] + s_data[1024 + p] + s_data[2048 + p] +
                      s_data[3072 + p] - CAP2 * (float)ncap;
            int iyp = tileY * 16 + (p >> 4);
            int ixp = tileX * 16 + (p & 15);
            atomicAdd(&logp[iyp * RENDER + ixp], v);
        }
    }

    // ---- completion: release logp atomics, bump per-tile counter ----
    __threadfence();                      // all threads: order logp adds
    __syncthreads();                      // before thread 0's counter RMW
    if (tid == 0)
        s_last = (atomicAdd(&done[tile], 1) == FACE_SLICES - 1) ? 1 : 0;
    __syncthreads();                      // s_last is block-uniform

    if (s_last) {
        // ---- fused final for this tile (runs in exactly one unit) ----
        __threadfence();                  // acquire side of the handshake
        {
            int p = tid;                  // tile-local pixel 0..255
            int iyp = tileY * 16 + (p >> 4);
            int ixp = tileX * 16 + (p & 15);
            // coherent RMW read: immune to cross-XCD L2 staleness
            float lp = atomicAdd(&logp[iyp * RENDER + ixp], 0.0f);
            s_si[p] = 1.0f - __builtin_amdgcn_exp2f(lp);
        }
        __syncthreads();
        // nearest-resize + crop + SSE over the tile's exclusive 40x40 patch:
        // out rows [tileY*40, +40) map back to render rows 16*tileY..+15.
        float d2 = 0.0f;
        for (int q = tid; q < 1600; q += 256) {
            int ro = q / 40, co = q - ro * 40;
            int Rr = tileY * 40 + ro;     // < 480 (tileY <= 11)
            int Cc = tileX * 40 + co;     // < 640
            int ir = (2 * Rr + 1) / 5;    // jax nearest, exact
            int ic = (2 * Cc + 1) / 5;
            float si = s_si[(ir & 15) * 16 + (ic & 15)];
            int idx = Rr * IMG_W + Cc;
            out[1 + idx] = si;
            float df = si - mask[idx];
            d2 = fmaf(df, df, d2);
        }
        #pragma unroll
        for (int off = 32; off > 0; off >>= 1) d2 += __shfl_down(d2, off, 64);
        if (lane == 0) s_red[wv] = d2;
        __syncthreads();
        if (tid == 0)
            atomicAdd(out, s_red[0] + s_red[1] + s_red[2] + s_red[3]);
    }
}

extern "C" void kernel_launch(void* const* d_in, const int* in_sizes, int n_in,
                              void* d_out, int out_size, void* d_ws, size_t ws_size,
                              hipStream_t stream) {
    const float* dof   = (const float*)d_in[0];
    const float* verts = (const float*)d_in[1];
    const int*   faces = (const int*)d_in[2];
    const float* Km    = (const float*)d_in[3];
    const float* mask  = (const float*)d_in[4];
    float* out = (float*)d_out;

    char* ws = (char*)d_ws;
    float* fdata = (float*)(ws + WS_FD_OFF);
    float* logp  = (float*)(ws + WS_LOGP_OFF);
    int*   done  = (int*)(ws + WS_DONE_OFF);

    k_prep<<<16 + TILES_LIVE, 256, 0, stream>>>(dof, verts, faces, Km,
                                                fdata, logp, done, out);
    k_raster<<<N_UNITS, 256, 0, stream>>>(fdata, logp, done, mask, out);
}

// Round 7
// 116.767 us; speedup vs baseline: 2.3267x; 2.3267x over previous
//
#include <hip/hip_runtime.h>
#include <math.h>

#define RENDER 256
#define IMG_H 480
#define IMG_W 640
#define NV 2048
#define NF 4096
#define FACE_SLICES 16
#define FACES_PER_SLICE (NF / FACE_SLICES)       // 256
#define TILES_X 16
#define TILES_Y_LIVE 12            // crop samples render rows <= 191 only:
                                   // (2*479+1)/5 = 191 -> tileY >= 12 is dead
#define TILES_LIVE (TILES_X * TILES_Y_LIVE)       // 192
#define N_UNITS (TILES_LIVE * FACE_SLICES)        // 3072 units
#define UNIT_HASH 2053             // gcd(2053,3072)=1 -> bijection mod 3072

#define SIGMA_INV 2.0f                            // 1/SIGMA, SIGMA=0.5
#define CAP 13.815510557964274f                   // -log(1e-6)
#define LOG2E 1.4426950408889634f
#define ZK 2.8853900817779268f                    // SIGMA_INV * LOG2E
#define CAP2 19.931568569324174f                  // CAP * LOG2E = log2(1e6)
#define ECAP 999999.0f                            // 1e6 - 1: min(1+e,1e6) = 1+min(e,ECAP)
#define SKIP_PIX -26.0f                           // per-px contribution < 2.1e-8 in log2
// Per-edge exact tile bound (verified R1/R5): over the 16x16 tile's pixel
// centers (tile-center +/- 7.5 px each axis), edge-line value d_k varies by
// at most r_k = 7.5*(|A_k|+|B_k|).
//   capped: min_k (d_k(center) - r_k) > CAP2      -> every px saturated
//   skip  : min_k (d_k(center) + r_k) < SKIP_PIX  -> every px negligible

// ws layout:
//   [0, 3MB)  partial : 3072 units * 256 floats. partial[unit][px] is the
//             unit's log2-domain contribution to its tile's pixel px
//             (including the unit's -CAP2*ncap term). Written non-atomically
//             by every unit in full (empty units write zeros) -> no zeroing
//             pass, no atomics, no fences. k_final sums the 16 slices.
#define WS_PART_OFF 0

// ---------------- kernel 1: fused setup + raster -------------------------
// 3072 blocks x 256 threads (4 waves): 192 live tiles x 16 face-slices,
// block -> unit via odd-multiplier hash (bijection) so heavy central tiles
// scatter across CUs.
// Stage A: SE3 exp (redundant per thread) + project all 2048 verts into LDS
//          (8 per thread). ~1 us aggregate redundancy -- buys one launch
//          boundary (~12-18 us) by eliminating k_prep.
// Stage B: classify the slice's 256 faces (1/thread): compute edge coeffs
//          in-register (bit-identical sequence to the old k_prep), per-edge
//          interval cull at tile center, ballot-compact survivors into LDS.
// Stage C: wave-split survivor eval, 4 px/lane, product-domain accumulation
//          (verified R1/R5 path).
// Stage D: LDS-reduce the 4 wave partials; write the unit's 256-float
//          partial row (plain coalesced stores, no atomics).
__global__ __launch_bounds__(256) void k_raster(const float* __restrict__ dof,
                                                const float* __restrict__ verts,
                                                const int* __restrict__ faces,
                                                const float* __restrict__ Km,
                                                float* __restrict__ partial) {
    __shared__ float sxy[NV * 2];   // 16 KB projected verts
    // 16 KB dual use: survivors (slots 0..259 of 12 floats = 3120 floats),
    // then 4 waves * 1024 tile-local-pixel reduction floats
    __shared__ float s_data[4096];
    __shared__ int s_n;
    __shared__ int s_ncap;

    const int tid = threadIdx.x;

    // ---- stage A: SE3 exp + projection (redundant per block) ----
    {
        float v0 = dof[0], v1 = dof[1], v2 = dof[2];
        float w0 = dof[3], w1 = dof[4], w2 = dof[5];
        float th2 = w0 * w0 + w1 * w1 + w2 * w2;
        float th = sqrtf(th2 + 1e-30f);
        bool small = th < 1e-4f;
        float th_s = small ? 1.0f : th;
        float th2_s = small ? 1.0f : th2;
        float A = small ? (1.0f - th2 / 6.0f) : (sinf(th_s) / th_s);
        float B = small ? (0.5f - th2 / 24.0f) : ((1.0f - cosf(th_s)) / th2_s);
        float C = small ? (1.0f / 6.0f - th2 / 120.0f)
                        : ((th_s - sinf(th_s)) / (th2_s * th_s));
        float Kx[9] = {0.0f, -w2, w1, w2, 0.0f, -w0, -w1, w0, 0.0f};
        float w[3] = {w0, w1, w2};
        float R[9], V[9];
        for (int i = 0; i < 3; i++)
            for (int j = 0; j < 3; j++) {
                float K2 = w[i] * w[j] - (i == j ? th2 : 0.0f);
                float id = (i == j) ? 1.0f : 0.0f;
                R[i * 3 + j] = id + A * Kx[i * 3 + j] + B * K2;
                V[i * 3 + j] = id + B * Kx[i * 3 + j] + C * K2;
            }
        float t0 = V[0] * v0 + V[1] * v1 + V[2] * v2;
        float t1 = V[3] * v0 + V[4] * v1 + V[5] * v2;
        float t2 = V[6] * v0 + V[7] * v1 + V[8] * v2;
        float K00 = Km[0], K01 = Km[1], K02 = Km[2];
        float K10 = Km[3], K11 = Km[4], K12 = Km[5];
        float K20 = Km[6], K21 = Km[7], K22 = Km[8];
        const float scale = 256.0f / 640.0f;
        for (int n = tid; n < NV; n += 256) {
            float vx = verts[n * 3], vy = verts[n * 3 + 1], vz = verts[n * 3 + 2];
            float cx = R[0] * vx + R[1] * vy + R[2] * vz + t0;
            float cy = R[3] * vx + R[4] * vy + R[5] * vz + t1;
            float cz = R[6] * vx + R[7] * vy + R[8] * vz + t2;
            float u = K00 * cx + K01 * cy + K02 * cz;
            float v = K10 * cx + K11 * cy + K12 * cz;
            float ww = K20 * cx + K21 * cy + K22 * cz;
            float rw = __builtin_amdgcn_rcpf(ww) * scale;   // ~1e-7 rel: 2e-5 px
            sxy[n * 2]     = u * rw;
            sxy[n * 2 + 1] = v * rw;
        }
    }
    if (tid == 0) { s_n = 0; s_ncap = 0; }
    __syncthreads();

    const int unit = (int)((blockIdx.x * UNIT_HASH) % N_UNITS);
    const int tile = unit >> 4;            // 0..191 (row-major, 16 wide)
    const int slice = unit & 15;
    const int tileX = tile & 15;
    const int tileY = tile >> 4;           // 0..11
    const float cxc = tileX * 16 + 8.0f;
    const float cyc = tileY * 16 + 8.0f;
    const int lane = tid & 63;

    // ---- stage B: per-face coeffs + interval cull + ballot-compact ----
    {
        int f = slice * FACES_PER_SLICE + tid;
        int i0 = faces[f * 3], i1 = faces[f * 3 + 1], i2 = faces[f * 3 + 2];
        float x0 = sxy[i0 * 2], y0 = sxy[i0 * 2 + 1];
        float x1 = sxy[i1 * 2], y1 = sxy[i1 * 2 + 1];
        float x2 = sxy[i2 * 2], y2 = sxy[i2 * 2 + 1];
        float ex0 = x1 - x0, ey0 = y1 - y0;
        float ex1 = x2 - x1, ey1 = y2 - y1;
        float ex2 = x0 - x2, ey2 = y0 - y2;
        float area2 = ex0 * (-ey2) - ey0 * (-ex2);
        float sgn = (area2 >= 0.0f) ? 1.0f : -1.0f;
        auto mkedge = [&](float exk, float eyk, float axk, float ayk) {
            float elen = sqrtf(exk * exk + eyk * eyk) + 1e-9f;
            float c0 = exk * ayk - eyk * axk;
            float inv = sgn / elen * ZK;         // prescale to log2 domain
            float Ac = exk * inv;                // A (py coeff)
            float Bc = -eyk * inv;               // B (px coeff)
            return make_float4(Ac, Bc, -c0 * inv,
                               7.5f * (fabsf(Ac) + fabsf(Bc)));
        };
        float4 e0 = mkedge(ex0, ey0, x0, y0);
        float4 e1 = mkedge(ex1, ey1, x1, y1);
        float4 e2 = mkedge(ex2, ey2, x2, y2);
        float d0 = fmaf(e0.y, cxc, fmaf(e0.x, cyc, e0.z));
        float d1 = fmaf(e1.y, cxc, fmaf(e1.x, cyc, e1.z));
        float d2 = fmaf(e2.y, cxc, fmaf(e2.x, cyc, e2.z));
        float capm = fminf(d0 - e0.w, fminf(d1 - e1.w, d2 - e2.w));
        float skpm = fminf(d0 + e0.w, fminf(d1 + e1.w, d2 + e2.w));
        bool capped = capm > CAP2;                   // saturated at every px
        bool live = (!capped) && (skpm > SKIP_PIX);  // else negligible everywhere
        unsigned long long mcap = __ballot(capped);
        unsigned long long mliv = __ballot(live);
        int base = 0;
        if (lane == 0) {
            base = atomicAdd(&s_n, __popcll(mliv));
            if (mcap) atomicAdd(&s_ncap, __popcll(mcap));
        }
        base = __shfl(base, 0, 64);
        if (live) {
            int pos = base + __popcll(mliv & ((1ull << lane) - 1ull));
            float4* dst = (float4*)(s_data + pos * 12);
            dst[0] = e0; dst[1] = e1; dst[2] = e2;
        }
    }
    __syncthreads();

    const int n = s_n;
    const int ncap = s_ncap;

    // ---- stage C: wave-split survivor eval, 4 px/lane, product domain ----
    const int wv = tid >> 6;
    const int row = lane >> 2;                       // 0..15
    const int col0 = lane & 3;                       // + {0,4,8,12}
    const float py = (float)(tileY * 16 + row) + 0.5f;
    const float px0 = (float)(tileX * 16 + col0) + 0.5f;

    float pm[4] = {1.0f, 1.0f, 1.0f, 1.0f};          // mantissa products
    int   pe[4] = {0, 0, 0, 0};                      // stripped exponents
    const float4* sd = (const float4*)s_data;
    if (wv < n) {
        float4 c0 = sd[wv * 3 + 0], c1 = sd[wv * 3 + 1], c2 = sd[wv * 3 + 2];
        int it = 0;
        for (int i = wv; i < n; i += 4) {
            // prefetch slot i+4 (slot <= 259 -> float < 3120 < 4096; value
            // discarded at loop exit when i+4 >= n)
            float4 n0 = sd[(i + 4) * 3 + 0];
            float4 n1 = sd[(i + 4) * 3 + 1];
            float4 n2 = sd[(i + 4) * 3 + 2];
            float t0p = fmaf(c0.x, py, c0.z);  // py-terms shared by the 4 px
            float t1p = fmaf(c1.x, py, c1.z);
            float t2p = fmaf(c2.x, py, c2.z);
            #pragma unroll
            for (int k = 0; k < 4; ++k) {
                float px = px0 + (float)(4 * k);
                float z = fminf(fmaf(c0.y, px, t0p),
                          fminf(fmaf(c1.y, px, t1p), fmaf(c2.y, px, t2p)));
                float e = fminf(__builtin_amdgcn_exp2f(z), ECAP);
                pm[k] = fmaf(pm[k], e, pm[k]);       // pm *= (1 + e), capped
            }
            if (((++it) & 3) == 0) {                 // strip exp every 4 faces
                #pragma unroll
                for (int k = 0; k < 4; ++k) {
                    unsigned b = __float_as_uint(pm[k]);
                    pe[k] += (int)(b >> 23) - 127;
                    pm[k] = __uint_as_float((b & 0x007fffffu) | 0x3f800000u);
                }
            }
            c0 = n0; c1 = n1; c2 = n2;
        }
    }
    float acc[4];
    #pragma unroll
    for (int k = 0; k < 4; ++k)
        acc[k] = -((float)pe[k] + __builtin_amdgcn_logf(pm[k]));  // -log2(prod)

    // ---- stage D: LDS-reduce 4 wave partials, plain store of unit row ----
    __syncthreads();                      // all waves done reading survivors
    {
        int base = wv * 1024 + row * 16 + col0;      // tile-local pixel index
        s_data[base + 0]  = acc[0];
        s_data[base + 4]  = acc[1];
        s_data[base + 8]  = acc[2];
        s_data[base + 12] = acc[3];
    }
    __syncthreads();
    {
        int p = tid;                                  // tile-local pixel 0..255
        float v = s_data[p] + s_data[1024 + p] + s_data[2048 + p] +
                  s_data[3072 + p] - CAP2 * (float)ncap;
        partial[unit * 256 + p] = v;      // coalesced, non-atomic, full row
    }
}

// ---------------- kernel 2: sum slices + resize + crop + SSE -------------
__global__ __launch_bounds__(256) void k_final(const float* __restrict__ partial,
                                               const float* __restrict__ mask,
                                               float* __restrict__ out) {
    int idx = blockIdx.x * 256 + threadIdx.x;   // 0 .. 307199
    int r = idx / IMG_W;
    int c = idx - r * IMG_W;
    // jax nearest: in = floor((out+0.5)*256/640) == (2*out+1)/5 exactly
    int ir = (2 * r + 1) / 5;                   // <= 191
    int ic = (2 * c + 1) / 5;                   // <= 255
    int tile = (ir >> 4) * 16 + (ic >> 4);      // live tile 0..191
    int base = tile * (16 * 256) + (ir & 15) * 16 + (ic & 15);
    float lp = 0.0f;
    #pragma unroll
    for (int s = 0; s < FACE_SLICES; ++s)
        lp += partial[base + s * 256];          // L2-resident (3 MB)
    // lp is log2-domain: si = 1 - 2^lp
    float si = 1.0f - __builtin_amdgcn_exp2f(lp);
    out[1 + idx] = si;
    float diff = si - mask[idx];
    float d2 = diff * diff;
    #pragma unroll
    for (int off = 32; off > 0; off >>= 1) d2 += __shfl_down(d2, off, 64);
    __shared__ float sred[4];
    int lane = threadIdx.x & 63;
    int wv = threadIdx.x >> 6;
    if (lane == 0) sred[wv] = d2;
    __syncthreads();
    if (threadIdx.x == 0)
        atomicAdd(out, sred[0] + sred[1] + sred[2] + sred[3]);
}

extern "C" void kernel_launch(void* const* d_in, const int* in_sizes, int n_in,
                              void* d_out, int out_size, void* d_ws, size_t ws_size,
                              hipStream_t stream) {
    const float* dof   = (const float*)d_in[0];
    const float* verts = (const float*)d_in[1];
    const int*   faces = (const int*)d_in[2];
    const float* Km    = (const float*)d_in[3];
    const float* mask  = (const float*)d_in[4];
    float* out = (float*)d_out;

    char* ws = (char*)d_ws;
    float* partial = (float*)(ws + WS_PART_OFF);

    k_raster<<<N_UNITS, 256, 0, stream>>>(dof, verts, faces, Km, partial);
    k_final<<<(IMG_H * IMG_W) / 256, 256, 0, stream>>>(partial, mask, out);
}

// Round 8
// 92.206 us; speedup vs baseline: 2.9464x; 1.2664x over previous
//
#include <hip/hip_runtime.h>
#include <math.h>

#define RENDER 256
#define IMG_H 480
#define IMG_W 640
#define NV 2048
#define NF 4096
#define FACE_SLICES 16
#define FACES_PER_SLICE (NF / FACE_SLICES)       // 256
#define TILES_X 16
#define TILES_Y_LIVE 12            // crop samples render rows <= 191 only:
                                   // (2*479+1)/5 = 191 -> tileY >= 12 is dead
#define TILES_LIVE (TILES_X * TILES_Y_LIVE)       // 192
#define N_UNITS (TILES_LIVE * FACE_SLICES)        // 3072 units
#define UNIT_HASH 2053             // gcd(2053,3072)=1 -> bijection mod 3072

#define SIGMA_INV 2.0f                            // 1/SIGMA, SIGMA=0.5
#define CAP 13.815510557964274f                   // -log(1e-6)
#define LOG2E 1.4426950408889634f
#define ZK 2.8853900817779268f                    // SIGMA_INV * LOG2E
#define CAP2 19.931568569324174f                  // CAP * LOG2E = log2(1e6)
#define ECAP 999999.0f                            // 1e6 - 1: min(1+e,1e6) = 1+min(e,ECAP)
#define SKIP_PIX -26.0f                           // per-px contribution < 2.1e-8 in log2
// Per-edge exact tile bound (verified R1/R5/R6): over the 16x16 tile's pixel
// centers (tile-center +/- 7.5 px each axis), edge-line value d_k varies by
// at most r_k = 7.5*(|A_k|+|B_k|), stored in the .w lane of each edge quad.
//   capped: min_k (d_k(center) - r_k) > CAP2      -> every px saturated
//   skip  : min_k (d_k(center) + r_k) < SKIP_PIX  -> every px negligible

// ws layout:
//   [0, 192KB)       fdata : 4096 faces * 12 floats (3 edges * {A,B,C,r})
//   [192KB, 448KB)   logp  : 65536 floats (log2-domain; rows 0..191 used)
//   [448KB, +768B)   done  : 192 ints, per-tile completion counters
#define WS_FD_OFF    0
#define WS_LOGP_OFF  (192 * 1024)
#define WS_DONE_OFF  (448 * 1024)

// ---------------- kernel 1: fused setup ----------------------------------
// blocks 0..15   : SE3 exp + project verts into LDS + per-face edge coeffs
// blocks 16..207 : zero logp rows 0..191; block 16 also zeros out[0] and the
//                  192 per-tile completion counters (stream-ordered).
__global__ __launch_bounds__(256) void k_prep(const float* __restrict__ dof,
                                              const float* __restrict__ verts,
                                              const int* __restrict__ faces,
                                              const float* __restrict__ Km,
                                              float* __restrict__ fdata,
                                              float* __restrict__ logp,
                                              int* __restrict__ done,
                                              float* __restrict__ out) {
    if (blockIdx.x >= 16) {
        logp[(blockIdx.x - 16) * 256 + threadIdx.x] = 0.0f;
        if (blockIdx.x == 16) {
            if (threadIdx.x == 0) out[0] = 0.0f;
            if (threadIdx.x < TILES_LIVE) done[threadIdx.x] = 0;
        }
        return;
    }

    __shared__ float sxy[NV * 2];   // 16 KB projected verts

    float v0 = dof[0], v1 = dof[1], v2 = dof[2];
    float w0 = dof[3], w1 = dof[4], w2 = dof[5];
    float th2 = w0 * w0 + w1 * w1 + w2 * w2;
    float th = sqrtf(th2 + 1e-30f);
    bool small = th < 1e-4f;
    float th_s = small ? 1.0f : th;
    float th2_s = small ? 1.0f : th2;
    float A = small ? (1.0f - th2 / 6.0f) : (sinf(th_s) / th_s);
    float B = small ? (0.5f - th2 / 24.0f) : ((1.0f - cosf(th_s)) / th2_s);
    float C = small ? (1.0f / 6.0f - th2 / 120.0f)
                    : ((th_s - sinf(th_s)) / (th2_s * th_s));
    float Kx[9] = {0.0f, -w2, w1, w2, 0.0f, -w0, -w1, w0, 0.0f};
    float w[3] = {w0, w1, w2};
    float R[9], V[9];
    for (int i = 0; i < 3; i++)
        for (int j = 0; j < 3; j++) {
            float K2 = w[i] * w[j] - (i == j ? th2 : 0.0f);
            float id = (i == j) ? 1.0f : 0.0f;
            R[i * 3 + j] = id + A * Kx[i * 3 + j] + B * K2;
            V[i * 3 + j] = id + B * Kx[i * 3 + j] + C * K2;
        }
    float t0 = V[0] * v0 + V[1] * v1 + V[2] * v2;
    float t1 = V[3] * v0 + V[4] * v1 + V[5] * v2;
    float t2 = V[6] * v0 + V[7] * v1 + V[8] * v2;
    float K00 = Km[0], K01 = Km[1], K02 = Km[2];
    float K10 = Km[3], K11 = Km[4], K12 = Km[5];
    float K20 = Km[6], K21 = Km[7], K22 = Km[8];
    const float scale = 256.0f / 640.0f;

    for (int n = threadIdx.x; n < NV; n += 256) {
        float vx = verts[n * 3], vy = verts[n * 3 + 1], vz = verts[n * 3 + 2];
        float cx = R[0] * vx + R[1] * vy + R[2] * vz + t0;
        float cy = R[3] * vx + R[4] * vy + R[5] * vz + t1;
        float cz = R[6] * vx + R[7] * vy + R[8] * vz + t2;
        float u = K00 * cx + K01 * cy + K02 * cz;
        float v = K10 * cx + K11 * cy + K12 * cz;
        float ww = K20 * cx + K21 * cy + K22 * cz;
        float rw = __builtin_amdgcn_rcpf(ww) * scale;   // rel err ~1e-7: 2e-5 px
        sxy[n * 2]     = u * rw;
        sxy[n * 2 + 1] = v * rw;
    }
    __syncthreads();

    int f = blockIdx.x * 256 + threadIdx.x;
    int i0 = faces[f * 3], i1 = faces[f * 3 + 1], i2 = faces[f * 3 + 2];
    float x0 = sxy[i0 * 2], y0 = sxy[i0 * 2 + 1];
    float x1 = sxy[i1 * 2], y1 = sxy[i1 * 2 + 1];
    float x2 = sxy[i2 * 2], y2 = sxy[i2 * 2 + 1];
    float ex[3] = {x1 - x0, x2 - x1, x0 - x2};
    float ey[3] = {y1 - y0, y2 - y1, y0 - y2};
    float ax[3] = {x0, x1, x2};
    float ay[3] = {y0, y1, y2};
    float area2 = ex[0] * (-ey[2]) - ey[0] * (-ex[2]);
    float sgn = (area2 >= 0.0f) ? 1.0f : -1.0f;
    float* o = fdata + f * 12;
    for (int k = 0; k < 3; k++) {
        float elen = sqrtf(ex[k] * ex[k] + ey[k] * ey[k]) + 1e-9f;
        float c0 = ex[k] * ay[k] - ey[k] * ax[k];
        float inv = sgn / elen * ZK;       // prescale into log2 domain
        float Ac = ex[k] * inv;            // A (py coeff)
        float Bc = -ey[k] * inv;           // B (px coeff)
        o[k * 4 + 0] = Ac;
        o[k * 4 + 1] = Bc;
        o[k * 4 + 2] = -c0 * inv;          // C
        o[k * 4 + 3] = 7.5f * (fabsf(Ac) + fabsf(Bc));   // r_k tile radius
    }
}

// ---------------- kernel 2: raster + fused final, FENCE-FREE -------------
// R6 structure (correctness-validated there) minus the __threadfence()
// storm that caused R6's 212 us (786K per-thread device fences -> L1/L2
// invalidate flood; VALUBusy 4.9%, FETCH 2x).
// Coherence argument without fences:
//   * every logp access is a device-scope atomic (atomicAdd), coherent at
//     the address's home-L2 point by default [m20];
//   * each unit's logp-adds are DRAINED (vmcnt=0, made explicit by inline
//     asm + guaranteed by the s_waitcnt the compiler emits before
//     s_barrier) before thread 0 issues the done[tile] counter atomic;
//   * the last unit (counter returns 15) therefore observes a counter
//     value that happens-after all 16 units' completed logp-adds; it
//     re-reads logp via atomic RMW (atomicAdd(p, 0.0f)) at the same
//     coherent point. No fences required anywhere.
__global__ __launch_bounds__(256) void k_raster(const float* __restrict__ fdata,
                                                float* __restrict__ logp,
                                                int* __restrict__ done,
                                                const float* __restrict__ mask,
                                                float* __restrict__ out) {
    // 16 KB, dual use:
    //   survivors: slots 0..259 of 12 floats  (3120 floats)
    //   reduction: 4 waves * 1024 tile-local-pixel floats (4096 floats)
    __shared__ float s_data[4096];
    __shared__ float s_si[256];
    __shared__ float s_red[4];
    __shared__ int s_n;
    __shared__ int s_ncap;
    __shared__ int s_last;
    const int tid = threadIdx.x;
    if (tid == 0) { s_n = 0; s_ncap = 0; }
    __syncthreads();

    const int unit = (int)((blockIdx.x * UNIT_HASH) % N_UNITS);
    const int tile = unit >> 4;            // 0..191 (row-major, 16 wide)
    const int slice = unit & 15;
    const int tileX = tile & 15;
    const int tileY = tile >> 4;           // 0..11
    const float cx = tileX * 16 + 8.0f;
    const float cy = tileY * 16 + 8.0f;
    const float4* __restrict__ fd4 = (const float4*)fdata;
    const int lane = tid & 63;

    // ---- phase 1: per-edge interval cull + ballot-compact ----
    {
        int f = slice * FACES_PER_SLICE + tid;
        float4 e0 = fd4[f * 3 + 0];
        float4 e1 = fd4[f * 3 + 1];
        float4 e2 = fd4[f * 3 + 2];
        float d0 = fmaf(e0.y, cx, fmaf(e0.x, cy, e0.z));
        float d1 = fmaf(e1.y, cx, fmaf(e1.x, cy, e1.z));
        float d2 = fmaf(e2.y, cx, fmaf(e2.x, cy, e2.z));
        float capm = fminf(d0 - e0.w, fminf(d1 - e1.w, d2 - e2.w));
        float skpm = fminf(d0 + e0.w, fminf(d1 + e1.w, d2 + e2.w));
        bool capped = capm > CAP2;                   // saturated at every px
        bool live = (!capped) && (skpm > SKIP_PIX);  // else negligible everywhere
        unsigned long long mcap = __ballot(capped);
        unsigned long long mliv = __ballot(live);
        int base = 0;
        if (lane == 0) {
            base = atomicAdd(&s_n, __popcll(mliv));
            if (mcap) atomicAdd(&s_ncap, __popcll(mcap));
        }
        base = __shfl(base, 0, 64);
        if (live) {
            int pos = base + __popcll(mliv & ((1ull << lane) - 1ull));
            float4* dst = (float4*)(s_data + pos * 12);
            dst[0] = e0; dst[1] = e1; dst[2] = e2;
        }
    }
    __syncthreads();

    const int n = s_n;
    const int ncap = s_ncap;
    const int wv = tid >> 6;
    const int row = lane >> 2;                       // 0..15
    const int col0 = lane & 3;                       // + {0,4,8,12}

    if (n != 0 || ncap != 0) {                       // non-empty unit
        // ---- phase 2: wave-split eval, 4 px/lane, product domain ----
        const float py = (float)(tileY * 16 + row) + 0.5f;
        const float px0 = (float)(tileX * 16 + col0) + 0.5f;

        float pm[4] = {1.0f, 1.0f, 1.0f, 1.0f};      // mantissa products
        int   pe[4] = {0, 0, 0, 0};                  // stripped exponents
        const float4* sd = (const float4*)s_data;
        if (wv < n) {
            float4 c0 = sd[wv * 3 + 0], c1 = sd[wv * 3 + 1], c2 = sd[wv * 3 + 2];
            int it = 0;
            for (int i = wv; i < n; i += 4) {
                // prefetch slot i+4 (slot <= 259 -> float < 3120 < 4096)
                float4 n0 = sd[(i + 4) * 3 + 0];
                float4 n1 = sd[(i + 4) * 3 + 1];
                float4 n2 = sd[(i + 4) * 3 + 2];
                float t0p = fmaf(c0.x, py, c0.z);  // py-terms shared by 4 px
                float t1p = fmaf(c1.x, py, c1.z);
                float t2p = fmaf(c2.x, py, c2.z);
                #pragma unroll
                for (int k = 0; k < 4; ++k) {
                    float px = px0 + (float)(4 * k);
                    float z = fminf(fmaf(c0.y, px, t0p),
                              fminf(fmaf(c1.y, px, t1p), fmaf(c2.y, px, t2p)));
                    float e = fminf(__builtin_amdgcn_exp2f(z), ECAP);
                    pm[k] = fmaf(pm[k], e, pm[k]);   // pm *= (1 + e), capped
                }
                if (((++it) & 3) == 0) {             // strip exp every 4 faces
                    #pragma unroll
                    for (int k = 0; k < 4; ++k) {
                        unsigned b = __float_as_uint(pm[k]);
                        pe[k] += (int)(b >> 23) - 127;
                        pm[k] = __uint_as_float((b & 0x007fffffu) | 0x3f800000u);
                    }
                }
                c0 = n0; c1 = n1; c2 = n2;
            }
        }
        float acc[4];
        #pragma unroll
        for (int k = 0; k < 4; ++k)
            acc[k] = -((float)pe[k] + __builtin_amdgcn_logf(pm[k]));

        // ---- phase 3: LDS-reduce 4 wave partials, 1 atomic per px ----
        __syncthreads();                  // all waves done reading survivors
        {
            int base = wv * 1024 + row * 16 + col0;
            s_data[base + 0]  = acc[0];
            s_data[base + 4]  = acc[1];
            s_data[base + 8]  = acc[2];
            s_data[base + 12] = acc[3];
        }
        __syncthreads();
        {
            int p = tid;                              // tile-local pixel
            float v = s_data[p] + s_data[1024 + p] + s_data[2048 + p] +
                      s_data[3072 + p] - CAP2 * (float)ncap;
            int iyp = tileY * 16 + (p >> 4);
            int ixp = tileX * 16 + (p & 15);
            atomicAdd(&logp[iyp * RENDER + ixp], v);
        }
    }

    // ---- completion: drain own atomics, bump per-tile counter ----
    // (NO __threadfence: see header comment. The explicit vmcnt drain makes
    // each thread's logp-adds globally complete before the barrier; thread
    // 0's counter atomic is issued strictly after.)
    asm volatile("s_waitcnt vmcnt(0)" ::: "memory");
    __syncthreads();
    if (tid == 0)
        s_last = (atomicAdd(&done[tile], 1) == FACE_SLICES - 1) ? 1 : 0;
    __syncthreads();                      // s_last is block-uniform

    if (s_last) {
        // ---- fused final for this tile (runs in exactly one unit) ----
        {
            int p = tid;                  // tile-local pixel 0..255
            int iyp = tileY * 16 + (p >> 4);
            int ixp = tileX * 16 + (p & 15);
            // atomic RMW read at the coherent point (cross-XCD safe)
            float lp = atomicAdd(&logp[iyp * RENDER + ixp], 0.0f);
            s_si[p] = 1.0f - __builtin_amdgcn_exp2f(lp);
        }
        __syncthreads();
        // nearest-resize + crop + SSE over the tile's exclusive 40x40 patch:
        // out rows [tileY*40, +40) map back to render rows 16*tileY..+15.
        float d2 = 0.0f;
        for (int q = tid; q < 1600; q += 256) {
            int ro = q / 40, co = q - ro * 40;
            int Rr = tileY * 40 + ro;     // < 480 (tileY <= 11)
            int Cc = tileX * 40 + co;     // < 640
            int ir = (2 * Rr + 1) / 5;    // jax nearest, exact
            int ic = (2 * Cc + 1) / 5;
            float si = s_si[(ir & 15) * 16 + (ic & 15)];
            int idx = Rr * IMG_W + Cc;
            out[1 + idx] = si;
            float df = si - mask[idx];
            d2 = fmaf(df, df, d2);
        }
        #pragma unroll
        for (int off = 32; off > 0; off >>= 1) d2 += __shfl_down(d2, off, 64);
        if (lane == 0) s_red[wv] = d2;
        __syncthreads();
        if (tid == 0)
            atomicAdd(out, s_red[0] + s_red[1] + s_red[2] + s_red[3]);
    }
}

extern "C" void kernel_launch(void* const* d_in, const int* in_sizes, int n_in,
                              void* d_out, int out_size, void* d_ws, size_t ws_size,
                              hipStream_t stream) {
    const float* dof   = (const float*)d_in[0];
    const float* verts = (const float*)d_in[1];
    const int*   faces = (const int*)d_in[2];
    const float* Km    = (const float*)d_in[3];
    const float* mask  = (const float*)d_in[4];
    float* out = (float*)d_out;

    char* ws = (char*)d_ws;
    float* fdata = (float*)(ws + WS_FD_OFF);
    float* logp  = (float*)(ws + WS_LOGP_OFF);
    int*   done  = (int*)(ws + WS_DONE_OFF);

    k_prep<<<16 + TILES_LIVE, 256, 0, stream>>>(dof, verts, faces, Km,
                                                fdata, logp, done, out);
    k_raster<<<N_UNITS, 256, 0, stream>>>(fdata, logp, done, mask, out);
}